// Round 1
// baseline (4619.608 us; speedup 1.0000x reference)
//
#include <hip/hip_runtime.h>
#include <cstddef>
#include <cstdint>
#include <math.h>

#define Bsz   2
#define Sdim  2048
#define Hn    16
#define Ddim  1024
#define DEPTH 64
#define Mrows (Bsz * Sdim)

// ---------------------------------------------------------------------------
// Register-blocked fp32 GEMM: Y = X(M,K) @ W(K,N) + bias(N)
// 64x64 tile per block, 256 threads, 4x4 per thread, BK=16.
// SPLIT=true stores Y in head-split layout (B,H,S,DEPTH).
// ---------------------------------------------------------------------------
template <bool SPLIT>
__device__ __forceinline__ void gemm_body(const float* __restrict__ X,
                                          const float* __restrict__ W,
                                          const float* __restrict__ bias,
                                          float* __restrict__ Y,
                                          int M, int N, int K)
{
    __shared__ float As[16][64];  // [k][m]
    __shared__ float Bs[16][64];  // [k][n]

    const int tid = threadIdx.x;
    const int m0 = blockIdx.y * 64;
    const int n0 = blockIdx.x * 64;

    const int tx = tid % 16;  // col group -> cols tx*4 .. +3
    const int ty = tid / 16;  // row group -> rows ty*4 .. +3

    // A tile load: thread -> (row, 4 consecutive k)
    const int a_row = tid / 4;
    const int a_k   = (tid % 4) * 4;
    // B tile load: thread -> (k, 4 consecutive cols)
    const int b_k   = tid / 16;
    const int b_col = (tid % 16) * 4;

    float acc[4][4] = {};

    for (int k0 = 0; k0 < K; k0 += 16) {
        float4 av = *reinterpret_cast<const float4*>(
            &X[(size_t)(m0 + a_row) * K + k0 + a_k]);
        As[a_k + 0][a_row] = av.x;
        As[a_k + 1][a_row] = av.y;
        As[a_k + 2][a_row] = av.z;
        As[a_k + 3][a_row] = av.w;

        float4 bv4 = *reinterpret_cast<const float4*>(
            &W[(size_t)(k0 + b_k) * N + n0 + b_col]);
        *reinterpret_cast<float4*>(&Bs[b_k][b_col]) = bv4;

        __syncthreads();

#pragma unroll
        for (int kk = 0; kk < 16; ++kk) {
            float a[4], b[4];
#pragma unroll
            for (int i = 0; i < 4; ++i) a[i] = As[kk][ty * 4 + i];
#pragma unroll
            for (int j = 0; j < 4; ++j) b[j] = Bs[kk][tx * 4 + j];
#pragma unroll
            for (int i = 0; i < 4; ++i)
#pragma unroll
                for (int j = 0; j < 4; ++j)
                    acc[i][j] += a[i] * b[j];
        }
        __syncthreads();
    }

#pragma unroll
    for (int i = 0; i < 4; ++i) {
        const int row = m0 + ty * 4 + i;
#pragma unroll
        for (int j = 0; j < 4; ++j) {
            const int col = n0 + tx * 4 + j;
            const float val = acc[i][j] + bias[col];
            if (SPLIT) {
                const int bb = row / Sdim;
                const int ss = row % Sdim;
                const int hh = col / DEPTH;
                const int dd = col % DEPTH;
                Y[(((size_t)bb * Hn + hh) * Sdim + ss) * DEPTH + dd] = val;
            } else {
                Y[(size_t)row * N + col] = val;
            }
        }
    }
}

__global__ __launch_bounds__(256) void proj_kernel(
    const float* __restrict__ q, const float* __restrict__ k,
    const float* __restrict__ v,
    const float* __restrict__ Wq, const float* __restrict__ Wk,
    const float* __restrict__ Wv,
    const float* __restrict__ bq, const float* __restrict__ bk,
    const float* __restrict__ bv,
    float* __restrict__ qh, float* __restrict__ kh, float* __restrict__ vh)
{
    const float* X; const float* W; const float* bias; float* Y;
    switch (blockIdx.z) {
        case 0:  X = q; W = Wq; bias = bq; Y = qh; break;
        case 1:  X = k; W = Wk; bias = bk; Y = kh; break;
        default: X = v; W = Wv; bias = bv; Y = vh; break;
    }
    gemm_body<true>(X, W, bias, Y, Mrows, Ddim, Ddim);
}

__global__ __launch_bounds__(256) void oproj_kernel(
    const float* __restrict__ ctx, const float* __restrict__ Wo,
    const float* __restrict__ bo, float* __restrict__ out)
{
    gemm_body<false>(ctx, Wo, bo, out, Mrows, Ddim, Ddim);
}

// ---------------------------------------------------------------------------
// Attention: one block (256 threads) per (b, h, q) row.
// Computes logits (causal), softmax (masked entries exactly 0 via fp32
// underflow semantics, same as reference), writes attn row, computes ctx row.
// ---------------------------------------------------------------------------
__global__ __launch_bounds__(256) void attn_kernel(
    const float* __restrict__ qh, const float* __restrict__ kh,
    const float* __restrict__ vh,
    float* __restrict__ attn, float* __restrict__ ctx)
{
    __shared__ float p[Sdim];
    __shared__ float qrow[DEPTH];
    __shared__ float red[4];
    __shared__ float ctxs[4][DEPTH];

    const int qi  = blockIdx.x;
    const int h   = blockIdx.y;
    const int b   = blockIdx.z;
    const int tid = threadIdx.x;
    const int lane = tid & 63;
    const int wave = tid >> 6;

    const size_t head_base = ((size_t)(b * Hn + h)) * Sdim * DEPTH;

    if (tid < DEPTH) qrow[tid] = qh[head_base + (size_t)qi * DEPTH + tid];
    __syncthreads();

    const float scale = 0.125f;  // 1/sqrt(64)

    // logits + local max
    float lmax = -INFINITY;
    for (int k = tid; k < Sdim; k += 256) {
        float lg = -INFINITY;
        if (k <= qi) {
            const float* krow = &kh[head_base + (size_t)k * DEPTH];
            float s = 0.f;
#pragma unroll
            for (int d = 0; d < DEPTH; ++d) s += qrow[d] * krow[d];
            lg = s * scale;
            lmax = fmaxf(lmax, lg);
        }
        p[k] = lg;
    }
#pragma unroll
    for (int off = 32; off > 0; off >>= 1)
        lmax = fmaxf(lmax, __shfl_down(lmax, off, 64));
    if (lane == 0) red[wave] = lmax;
    __syncthreads();
    const float mx = fmaxf(fmaxf(red[0], red[1]), fmaxf(red[2], red[3]));
    __syncthreads();

    // exp + local sum
    float lsum = 0.f;
    for (int k = tid; k < Sdim; k += 256) {
        float e = (k <= qi) ? expf(p[k] - mx) : 0.f;
        p[k] = e;
        lsum += e;
    }
#pragma unroll
    for (int off = 32; off > 0; off >>= 1)
        lsum += __shfl_down(lsum, off, 64);
    if (lane == 0) red[wave] = lsum;
    __syncthreads();
    const float inv = 1.f / (red[0] + red[1] + red[2] + red[3]);

    // normalize + write attn row
    const size_t arow = ((size_t)(b * Hn + h) * Sdim + qi) * Sdim;
    for (int k = tid; k < Sdim; k += 256) {
        const float pv = p[k] * inv;
        p[k] = pv;
        attn[arow + k] = pv;
    }
    __syncthreads();

    // ctx row: 4 groups of 64 lanes; lane d accumulates ctx[d]
    const int g = tid >> 6;
    const int d = tid & 63;
    float c = 0.f;
    for (int k = g; k <= qi; k += 4)
        c += p[k] * vh[head_base + (size_t)k * DEPTH + d];
    ctxs[g][d] = c;
    __syncthreads();
    if (tid < DEPTH) {
        const float val = ctxs[0][tid] + ctxs[1][tid] + ctxs[2][tid] + ctxs[3][tid];
        ctx[((size_t)b * Sdim + qi) * Ddim + h * DEPTH + tid] = val;
    }
}

// ---------------------------------------------------------------------------
extern "C" void kernel_launch(void* const* d_in, const int* in_sizes, int n_in,
                              void* d_out, int out_size, void* d_ws, size_t ws_size,
                              hipStream_t stream)
{
    (void)in_sizes; (void)n_in; (void)out_size; (void)ws_size;

    const float* v  = (const float*)d_in[0];
    const float* k  = (const float*)d_in[1];
    const float* q  = (const float*)d_in[2];
    // d_in[3] = mask (causal, implied structurally)
    const float* Wq = (const float*)d_in[4];
    const float* bq = (const float*)d_in[5];
    const float* Wk = (const float*)d_in[6];
    const float* bk = (const float*)d_in[7];
    const float* Wv = (const float*)d_in[8];
    const float* bv = (const float*)d_in[9];
    const float* Wo = (const float*)d_in[10];
    const float* bo = (const float*)d_in[11];

    float* out  = (float*)d_out;
    float* attn = out + (size_t)Bsz * Sdim * Ddim;

    const size_t sz = (size_t)Bsz * Sdim * Ddim;  // 4,194,304 floats
    float* ws  = (float*)d_ws;
    float* qh  = ws;
    float* kh  = qh + sz;
    float* vh  = kh + sz;
    float* ctx = vh + sz;

    dim3 gproj(Ddim / 64, Mrows / 64, 3);
    proj_kernel<<<gproj, 256, 0, stream>>>(q, k, v, Wq, Wk, Wv, bq, bk, bv,
                                           qh, kh, vh);

    dim3 gattn(Sdim, Hn, Bsz);
    attn_kernel<<<gattn, 256, 0, stream>>>(qh, kh, vh, attn, ctx);

    dim3 gout(Ddim / 64, Mrows / 64);
    oproj_kernel<<<gout, 256, 0, stream>>>(ctx, Wo, bo, out);
}

// Round 2
// 4066.534 us; speedup vs baseline: 1.1360x; 1.1360x over previous
//
#include <hip/hip_runtime.h>
#include <cstddef>
#include <cstdint>
#include <math.h>

#define Bsz   2
#define Sdim  2048
#define Hn    16
#define Ddim  1024
#define DEPTH 64
#define Mrows (Bsz * Sdim)
#define QTILES (Sdim / 64)

// ---------------------------------------------------------------------------
// Register-blocked fp32 GEMM: Y = X(M,K) @ W(K,N) + bias(N)
// 64x64 tile per block, 256 threads, 4x4 per thread, BK=16.
// SPLIT=true stores Y in head-split layout (B,H,S,DEPTH).
// ---------------------------------------------------------------------------
template <bool SPLIT>
__device__ __forceinline__ void gemm_body(const float* __restrict__ X,
                                          const float* __restrict__ W,
                                          const float* __restrict__ bias,
                                          float* __restrict__ Y,
                                          int M, int N, int K)
{
    __shared__ float As[16][64];  // [k][m]
    __shared__ float Bs[16][64];  // [k][n]

    const int tid = threadIdx.x;
    const int m0 = blockIdx.y * 64;
    const int n0 = blockIdx.x * 64;

    const int tx = tid % 16;
    const int ty = tid / 16;

    const int a_row = tid / 4;
    const int a_k   = (tid % 4) * 4;
    const int b_k   = tid / 16;
    const int b_col = (tid % 16) * 4;

    float acc[4][4] = {};

    for (int k0 = 0; k0 < K; k0 += 16) {
        float4 av = *reinterpret_cast<const float4*>(
            &X[(size_t)(m0 + a_row) * K + k0 + a_k]);
        As[a_k + 0][a_row] = av.x;
        As[a_k + 1][a_row] = av.y;
        As[a_k + 2][a_row] = av.z;
        As[a_k + 3][a_row] = av.w;

        float4 bv4 = *reinterpret_cast<const float4*>(
            &W[(size_t)(k0 + b_k) * N + n0 + b_col]);
        *reinterpret_cast<float4*>(&Bs[b_k][b_col]) = bv4;

        __syncthreads();

#pragma unroll
        for (int kk = 0; kk < 16; ++kk) {
            float a[4], b[4];
#pragma unroll
            for (int i = 0; i < 4; ++i) a[i] = As[kk][ty * 4 + i];
#pragma unroll
            for (int j = 0; j < 4; ++j) b[j] = Bs[kk][tx * 4 + j];
#pragma unroll
            for (int i = 0; i < 4; ++i)
#pragma unroll
                for (int j = 0; j < 4; ++j)
                    acc[i][j] += a[i] * b[j];
        }
        __syncthreads();
    }

#pragma unroll
    for (int i = 0; i < 4; ++i) {
        const int row = m0 + ty * 4 + i;
#pragma unroll
        for (int j = 0; j < 4; ++j) {
            const int col = n0 + tx * 4 + j;
            const float val = acc[i][j] + bias[col];
            if (SPLIT) {
                const int bb = row / Sdim;
                const int ss = row % Sdim;
                const int hh = col / DEPTH;
                const int dd = col % DEPTH;
                Y[(((size_t)bb * Hn + hh) * Sdim + ss) * DEPTH + dd] = val;
            } else {
                Y[(size_t)row * N + col] = val;
            }
        }
    }
}

__global__ __launch_bounds__(256) void proj_kernel(
    const float* __restrict__ q, const float* __restrict__ k,
    const float* __restrict__ v,
    const float* __restrict__ Wq, const float* __restrict__ Wk,
    const float* __restrict__ Wv,
    const float* __restrict__ bq, const float* __restrict__ bk,
    const float* __restrict__ bv,
    float* __restrict__ qh, float* __restrict__ kh, float* __restrict__ vh)
{
    const float* X; const float* W; const float* bias; float* Y;
    switch (blockIdx.z) {
        case 0:  X = q; W = Wq; bias = bq; Y = qh; break;
        case 1:  X = k; W = Wk; bias = bk; Y = kh; break;
        default: X = v; W = Wv; bias = bv; Y = vh; break;
    }
    gemm_body<true>(X, W, bias, Y, Mrows, Ddim, Ddim);
}

__global__ __launch_bounds__(256) void oproj_kernel(
    const float* __restrict__ ctx, const float* __restrict__ Wo,
    const float* __restrict__ bo, float* __restrict__ out)
{
    gemm_body<false>(ctx, Wo, bo, out, Mrows, Ddim, Ddim);
}

// ---------------------------------------------------------------------------
// Tiled attention: one block per 64-row Q-tile per (b,h).
// Pass 1: online row max/sum (stats replicated across the 16-thread row
// group via shfl_xor). Pass 2: recompute logits, p=exp(l-m)/s, write attn,
// LDS round-trip P, accumulate ctx = P*V (register-blocked 4x4).
// ---------------------------------------------------------------------------
__global__ __launch_bounds__(256) void attn_tile_kernel(
    const float* __restrict__ qh, const float* __restrict__ kh,
    const float* __restrict__ vh,
    float* __restrict__ attn, float* __restrict__ ctx)
{
    __shared__ float Qs[64][65];
    __shared__ float Ks[64][65];   // aliased as Ps in pass 2
    __shared__ float Vs[64][65];

    const int qt  = (QTILES - 1) - blockIdx.x;   // heavy tiles dispatch first
    const int h   = blockIdx.y;
    const int b   = blockIdx.z;
    const int tid = threadIdx.x;
    const int tx  = tid & 15;     // 4 cols: tx*4..+3
    const int ty  = tid >> 4;     // 4 rows: ty*4..+3

    const size_t head_base = ((size_t)(b * Hn + h)) * Sdim * DEPTH;
    const int q0 = qt * 64;
    const float scale = 0.125f;   // 1/sqrt(64)

    // load Q tile
    for (int i = tid; i < 64 * 16; i += 256) {
        const int r = i >> 4, c4 = (i & 15) << 2;
        *reinterpret_cast<float4*>(&Qs[r][c4]) =
            *reinterpret_cast<const float4*>(
                &qh[head_base + (size_t)(q0 + r) * DEPTH + c4]);
    }

    float m_r[4], s_r[4];
#pragma unroll
    for (int i = 0; i < 4; ++i) { m_r[i] = -INFINITY; s_r[i] = 0.f; }

    // ---------------- pass 1: stats ----------------
    for (int kt = 0; kt <= qt; ++kt) {
        __syncthreads();
        const int k0 = kt * 64;
        for (int i = tid; i < 64 * 16; i += 256) {
            const int r = i >> 4, c4 = (i & 15) << 2;
            *reinterpret_cast<float4*>(&Ks[r][c4]) =
                *reinterpret_cast<const float4*>(
                    &kh[head_base + (size_t)(k0 + r) * DEPTH + c4]);
        }
        __syncthreads();

        float acc[4][4] = {};
#pragma unroll
        for (int kk4 = 0; kk4 < 64; kk4 += 4) {
            float4 a4[4], b4[4];
#pragma unroll
            for (int i = 0; i < 4; ++i)
                a4[i] = *reinterpret_cast<const float4*>(&Qs[ty * 4 + i][kk4]);
#pragma unroll
            for (int j = 0; j < 4; ++j)
                b4[j] = *reinterpret_cast<const float4*>(&Ks[tx * 4 + j][kk4]);
#pragma unroll
            for (int i = 0; i < 4; ++i)
#pragma unroll
                for (int j = 0; j < 4; ++j)
                    acc[i][j] += a4[i].x * b4[j].x + a4[i].y * b4[j].y +
                                 a4[i].z * b4[j].z + a4[i].w * b4[j].w;
        }

        const bool diag = (kt == qt);
#pragma unroll
        for (int i = 0; i < 4; ++i) {
            const int qg = q0 + ty * 4 + i;
            float tmax = -INFINITY;
#pragma unroll
            for (int j = 0; j < 4; ++j) {
                float l = acc[i][j] * scale;
                if (diag && (kt * 64 + tx * 4 + j > qg)) l = -INFINITY;
                acc[i][j] = l;
                tmax = fmaxf(tmax, l);
            }
            tmax = fmaxf(tmax, __shfl_xor(tmax, 1, 64));
            tmax = fmaxf(tmax, __shfl_xor(tmax, 2, 64));
            tmax = fmaxf(tmax, __shfl_xor(tmax, 4, 64));
            tmax = fmaxf(tmax, __shfl_xor(tmax, 8, 64));

            const float mnew = fmaxf(m_r[i], tmax);
            float psum = 0.f;
#pragma unroll
            for (int j = 0; j < 4; ++j)
                psum += (acc[i][j] <= -1e37f) ? 0.f : expf(acc[i][j] - mnew);
            psum += __shfl_xor(psum, 1, 64);
            psum += __shfl_xor(psum, 2, 64);
            psum += __shfl_xor(psum, 4, 64);
            psum += __shfl_xor(psum, 8, 64);

            const float corr = (m_r[i] <= -1e37f) ? 0.f : expf(m_r[i] - mnew);
            s_r[i] = s_r[i] * corr + psum;
            m_r[i] = mnew;
        }
    }

    float inv_s[4];
#pragma unroll
    for (int i = 0; i < 4; ++i) inv_s[i] = 1.f / s_r[i];

    float accv[4][4] = {};  // ctx accumulator: rows ty*4+i, d-cols tx*4+j

    // ---------------- pass 2: attn write + PV ----------------
    for (int kt = 0; kt <= qt; ++kt) {
        __syncthreads();   // prior iteration done reading Ps/Vs
        const int k0 = kt * 64;
        for (int i = tid; i < 64 * 16; i += 256) {
            const int r = i >> 4, c4 = (i & 15) << 2;
            const size_t src = head_base + (size_t)(k0 + r) * DEPTH + c4;
            *reinterpret_cast<float4*>(&Ks[r][c4]) =
                *reinterpret_cast<const float4*>(&kh[src]);
            *reinterpret_cast<float4*>(&Vs[r][c4]) =
                *reinterpret_cast<const float4*>(&vh[src]);
        }
        __syncthreads();

        float acc[4][4] = {};
#pragma unroll
        for (int kk4 = 0; kk4 < 64; kk4 += 4) {
            float4 a4[4], b4[4];
#pragma unroll
            for (int i = 0; i < 4; ++i)
                a4[i] = *reinterpret_cast<const float4*>(&Qs[ty * 4 + i][kk4]);
#pragma unroll
            for (int j = 0; j < 4; ++j)
                b4[j] = *reinterpret_cast<const float4*>(&Ks[tx * 4 + j][kk4]);
#pragma unroll
            for (int i = 0; i < 4; ++i)
#pragma unroll
                for (int j = 0; j < 4; ++j)
                    acc[i][j] += a4[i].x * b4[j].x + a4[i].y * b4[j].y +
                                 a4[i].z * b4[j].z + a4[i].w * b4[j].w;
        }

        const bool diag = (kt == qt);
#pragma unroll
        for (int i = 0; i < 4; ++i) {
            const int qg = q0 + ty * 4 + i;
#pragma unroll
            for (int j = 0; j < 4; ++j) {
                float p;
                if (diag && (k0 + tx * 4 + j > qg)) p = 0.f;
                else p = expf(acc[i][j] * scale - m_r[i]) * inv_s[i];
                acc[i][j] = p;
            }
            // write attn row segment (float4, coalesced across tx)
            const size_t arow =
                ((size_t)(b * Hn + h) * Sdim + qg) * Sdim + k0 + tx * 4;
            float4 pv = make_float4(acc[i][0], acc[i][1], acc[i][2], acc[i][3]);
            *reinterpret_cast<float4*>(&attn[arow]) = pv;
        }

        __syncthreads();   // all threads done reading Ks
        float (*Ps)[65] = Ks;  // alias
#pragma unroll
        for (int i = 0; i < 4; ++i)
            *reinterpret_cast<float4*>(&Ps[ty * 4 + i][tx * 4]) =
                make_float4(acc[i][0], acc[i][1], acc[i][2], acc[i][3]);
        __syncthreads();

#pragma unroll
        for (int kk4 = 0; kk4 < 64; kk4 += 4) {
            float4 a4[4];
#pragma unroll
            for (int i = 0; i < 4; ++i)
                a4[i] = *reinterpret_cast<const float4*>(&Ps[ty * 4 + i][kk4]);
#pragma unroll
            for (int kk = 0; kk < 4; ++kk) {
                float4 b4 = *reinterpret_cast<const float4*>(&Vs[kk4 + kk][tx * 4]);
                const float av0 = (kk == 0) ? a4[0].x : (kk == 1) ? a4[0].y : (kk == 2) ? a4[0].z : a4[0].w;
                const float av1 = (kk == 0) ? a4[1].x : (kk == 1) ? a4[1].y : (kk == 2) ? a4[1].z : a4[1].w;
                const float av2 = (kk == 0) ? a4[2].x : (kk == 1) ? a4[2].y : (kk == 2) ? a4[2].z : a4[2].w;
                const float av3 = (kk == 0) ? a4[3].x : (kk == 1) ? a4[3].y : (kk == 2) ? a4[3].z : a4[3].w;
                accv[0][0] += av0 * b4.x; accv[0][1] += av0 * b4.y; accv[0][2] += av0 * b4.z; accv[0][3] += av0 * b4.w;
                accv[1][0] += av1 * b4.x; accv[1][1] += av1 * b4.y; accv[1][2] += av1 * b4.z; accv[1][3] += av1 * b4.w;
                accv[2][0] += av2 * b4.x; accv[2][1] += av2 * b4.y; accv[2][2] += av2 * b4.z; accv[2][3] += av2 * b4.w;
                accv[3][0] += av3 * b4.x; accv[3][1] += av3 * b4.y; accv[3][2] += av3 * b4.z; accv[3][3] += av3 * b4.w;
            }
        }
    }

    // write ctx in concat layout (B, S, D)
#pragma unroll
    for (int i = 0; i < 4; ++i) {
        const int qg = q0 + ty * 4 + i;
        float4 cv = make_float4(accv[i][0], accv[i][1], accv[i][2], accv[i][3]);
        *reinterpret_cast<float4*>(
            &ctx[((size_t)b * Sdim + qg) * Ddim + h * DEPTH + tx * 4]) = cv;
    }
}

// ---------------------------------------------------------------------------
extern "C" void kernel_launch(void* const* d_in, const int* in_sizes, int n_in,
                              void* d_out, int out_size, void* d_ws, size_t ws_size,
                              hipStream_t stream)
{
    (void)in_sizes; (void)n_in; (void)out_size; (void)ws_size;

    const float* v  = (const float*)d_in[0];
    const float* k  = (const float*)d_in[1];
    const float* q  = (const float*)d_in[2];
    const float* Wq = (const float*)d_in[4];
    const float* bq = (const float*)d_in[5];
    const float* Wk = (const float*)d_in[6];
    const float* bk = (const float*)d_in[7];
    const float* Wv = (const float*)d_in[8];
    const float* bv = (const float*)d_in[9];
    const float* Wo = (const float*)d_in[10];
    const float* bo = (const float*)d_in[11];

    float* out  = (float*)d_out;
    float* attn = out + (size_t)Bsz * Sdim * Ddim;

    const size_t sz = (size_t)Bsz * Sdim * Ddim;
    float* ws  = (float*)d_ws;
    float* qh  = ws;
    float* kh  = qh + sz;
    float* vh  = kh + sz;
    float* ctx = vh + sz;

    dim3 gproj(Ddim / 64, Mrows / 64, 3);
    proj_kernel<<<gproj, 256, 0, stream>>>(q, k, v, Wq, Wk, Wv, bq, bk, bv,
                                           qh, kh, vh);

    dim3 gattn(QTILES, Hn, Bsz);
    attn_tile_kernel<<<gattn, 256, 0, stream>>>(qh, kh, vh, attn, ctx);

    dim3 gout(Ddim / 64, Mrows / 64);
    oproj_kernel<<<gout, 256, 0, stream>>>(ctx, Wo, bo, out);
}